// Round 17
// baseline (105.122 us; speedup 1.0000x reference)
//
#include <hip/hip_runtime.h>
#include <hip/hip_bf16.h>

// Problem sizes (fixed by the reference)
#define S_LEN 256     // sequence length (t)
#define DM    512     // d_model (k / d)
#define DR    512     // d_rnn (s)

typedef float f4 __attribute__((ext_vector_type(4)));
typedef float f2 __attribute__((ext_vector_type(2)));

// Single fused kernel. grid(256) x 256: block = s-pair (XCD-banded).
//
// Phase 1 (lane = k-slice, COALESCED): wave w owns t in [64w, 64w+64).
//   Lane L holds W1[{s0,s1,DR+s0,DR+s1}][8L..8L+8) in 8 f4 regs (coalesced
//   loads, 32B lane stride). Per t: 2 coalesced f4 x-loads (the wave reads
//   one contiguous 2KB x row), 32 FMAs, 6-stage shfl_xor butterfly over 4
//   independent chains, wave-uniform activation math, one LDS write.
//   This replaces R15/R16's uncoalesced phase 1 (64 lines/inst, ~32K line
//   requests per CU ~= 25 us) with ~8K requests carrying 16x more data each.
//
// Phase 2: R11/R16's recurrence + y stream verbatim (measured 44.4 us).
__global__ __launch_bounds__(256) void k_fused(const float* __restrict__ x,
                                               const float* __restrict__ state0,
                                               const float* __restrict__ W1,
                                               const float* __restrict__ b1,
                                               const float* __restrict__ Lam,
                                               f4* __restrict__ out4) {
    const int bx  = blockIdx.x;                  // 0..255
    const int sp  = (bx & 7) * 32 + (bx >> 3);   // bijective XCD s-banding
    const int tid = threadIdx.x;
    const int s0  = sp * 2;
    const int s1  = sp * 2 + 1;
    const int wv  = tid >> 6;                    // wave 0..3
    const int ln  = tid & 63;                    // lane

    __shared__ f2 ac_l[2][S_LEN];                // {a, c} per (half, t)

    // ---- Phase 1 ----
    {
        const f4* __restrict__ W4 = reinterpret_cast<const f4*>(W1);
        const f4* __restrict__ x4 = reinterpret_cast<const f4*>(x);
        const int kb = ln * 2;                   // f4 index of lane's k-slice

        const f4 wi0a = W4[s0 * 128 + kb],        wi0b = W4[s0 * 128 + kb + 1];
        const f4 wi1a = W4[s1 * 128 + kb],        wi1b = W4[s1 * 128 + kb + 1];
        const f4 wr0a = W4[(DR + s0) * 128 + kb], wr0b = W4[(DR + s0) * 128 + kb + 1];
        const f4 wr1a = W4[(DR + s1) * 128 + kb], wr1b = W4[(DR + s1) * 128 + kb + 1];

        const float bi0 = b1[s0], bi1 = b1[s1];
        const float br0 = b1[DR + s0], br1 = b1[DR + s1];
        const float sof0 = log1pf(expf(Lam[s0]));
        const float sof1 = log1pf(expf(Lam[s1]));

#pragma unroll 4
        for (int tt = 0; tt < 64; ++tt) {
            const int t = wv * 64 + tt;
            const f4 xa = x4[t * 128 + kb];      // coalesced: wave spans 2KB row
            const f4 xb = x4[t * 128 + kb + 1];

            float p0, p1, p2, p3;
            p0  = xa.x * wi0a.x; p0 = fmaf(xa.y, wi0a.y, p0);
            p0  = fmaf(xa.z, wi0a.z, p0); p0 = fmaf(xa.w, wi0a.w, p0);
            p0  = fmaf(xb.x, wi0b.x, p0); p0 = fmaf(xb.y, wi0b.y, p0);
            p0  = fmaf(xb.z, wi0b.z, p0); p0 = fmaf(xb.w, wi0b.w, p0);
            p1  = xa.x * wi1a.x; p1 = fmaf(xa.y, wi1a.y, p1);
            p1  = fmaf(xa.z, wi1a.z, p1); p1 = fmaf(xa.w, wi1a.w, p1);
            p1  = fmaf(xb.x, wi1b.x, p1); p1 = fmaf(xb.y, wi1b.y, p1);
            p1  = fmaf(xb.z, wi1b.z, p1); p1 = fmaf(xb.w, wi1b.w, p1);
            p2  = xa.x * wr0a.x; p2 = fmaf(xa.y, wr0a.y, p2);
            p2  = fmaf(xa.z, wr0a.z, p2); p2 = fmaf(xa.w, wr0a.w, p2);
            p2  = fmaf(xb.x, wr0b.x, p2); p2 = fmaf(xb.y, wr0b.y, p2);
            p2  = fmaf(xb.z, wr0b.z, p2); p2 = fmaf(xb.w, wr0b.w, p2);
            p3  = xa.x * wr1a.x; p3 = fmaf(xa.y, wr1a.y, p3);
            p3  = fmaf(xa.z, wr1a.z, p3); p3 = fmaf(xa.w, wr1a.w, p3);
            p3  = fmaf(xb.x, wr1b.x, p3); p3 = fmaf(xb.y, wr1b.y, p3);
            p3  = fmaf(xb.z, wr1b.z, p3); p3 = fmaf(xb.w, wr1b.w, p3);

#pragma unroll
            for (int m = 1; m < 64; m <<= 1) {   // butterfly: all lanes get sums
                p0 += __shfl_xor(p0, m);
                p1 += __shfl_xor(p1, m);
                p2 += __shfl_xor(p2, m);
                p3 += __shfl_xor(p3, m);
            }

            // wave-uniform activation math (all lanes, no divergence)
            const float inp0 = 1.f / (1.f + expf(-(p0 + bi0)));
            const float inp1 = 1.f / (1.f + expf(-(p1 + bi1)));
            const float rec0 = 1.f / (1.f + expf(-(p2 + br0)));
            const float rec1 = 1.f / (1.f + expf(-(p3 + br1)));
            const float a0 = expf(-8.f * sof0 * rec0);
            const float a1 = expf(-8.f * sof1 * rec1);
            const float c0 = sqrtf(fmaxf(1.f - a0 * a0, 0.f)) * inp0;
            const float c1 = sqrtf(fmaxf(1.f - a1 * a1, 0.f)) * inp1;

            if (ln == 0) {
                f2 ac0; ac0.x = a0; ac0.y = c0;
                f2 ac1; ac1.x = a1; ac1.y = c1;
                ac_l[0][t] = ac0;
                ac_l[1][t] = ac1;
            }
        }
    }

    // ---- Phase 2: recurrence + y stream (thread = (half, dq)) ----
    const int half = tid >> 7;           // 0 or 1
    const int s    = sp * 2 + half;
    const int dq   = tid & 127;          // d/4

    const f4* __restrict__ st4 = reinterpret_cast<const f4*>(state0);
    f4 h = st4[s * 128 + dq];

    const f4* __restrict__ x4 = reinterpret_cast<const f4*>(x);
    f4 xv = x4[dq];                      // t = 0 prefetch

    __syncthreads();                     // ac_l ready

#pragma unroll 4
    for (int t = 0; t < S_LEN; ++t) {
        f4 xn;
        if (t + 1 < S_LEN) xn = x4[(t + 1) * 128 + dq];
        else xn = (f4)0.f;

        const f2 ac = ac_l[half][t];               // wave-uniform LDS broadcast
        const float at = ac.x, ct = ac.y;
        h.x = fmaf(at, h.x, ct * xv.x);
        h.y = fmaf(at, h.y, ct * xv.y);
        h.z = fmaf(at, h.z, ct * xv.z);
        h.w = fmaf(at, h.w, ct * xv.w);

        __builtin_nontemporal_store(h, &out4[(t * DR + s) * 128 + dq]);
        xv = xn;
    }
    // final state
    out4[(S_LEN * DR) * 128 + s * 128 + dq] = h;
}

extern "C" void kernel_launch(void* const* d_in, const int* in_sizes, int n_in,
                              void* d_out, int out_size, void* d_ws, size_t ws_size,
                              hipStream_t stream) {
    const float* x      = (const float*)d_in[0];
    const float* state0 = (const float*)d_in[1];
    const float* W1     = (const float*)d_in[2];
    const float* b1     = (const float*)d_in[3];
    const float* Lam    = (const float*)d_in[4];

    f4* out4 = (f4*)d_out;

    k_fused<<<dim3(256), 256, 0, stream>>>(x, state0, W1, b1, Lam, out4);
}